// Round 7
// baseline (405.689 us; speedup 1.0000x reference)
//
#include <hip/hip_runtime.h>
#include <hip/hip_bf16.h>

// CausalDiscoveryModule: B=256, N=512, E=32, IN=512, K=10
// out[b,i,j] = gate_b * sigmoid(logit) on per-(b,i)-row top-10 of j, else 0
// logit = sum_e (c_b^2 * emb_i)[e] * emb_j[e]
//
// R7 = R6's med3 two-pass, minus its three measured drags:
//  - collection: per-lane VGPR counter + predicated ds_write_b64 (no atomics)
//  - final order: quarters concatenated in ascending-j, exact strict-> insert
//    over ~10 candidates (branchless, masked no-ops). No u64 sort.
//  - epilogue: R5-style fill -> vmcnt(0) -> scatter, back-to-back (L2-hot,
//    WRITE_SIZE must return to 262144 KB).
//  - LDS overlay (merge lists alias candidate buffers): 21.5 KB -> 7 blk/CU.

#define NUM_VARS 512
#define EMBED_DIM 32
#define IN_DIM 512
#define BATCH 256

typedef float nf4 __attribute__((ext_vector_type(4)));
typedef float f2 __attribute__((ext_vector_type(2)));

// ---------------- K1: context MLP -> w = c^2 [256][32], gate [256] ----------
__global__ __launch_bounds__(256) void cdm_k1(
    const float* __restrict__ ctx, const float* __restrict__ W1,
    const float* __restrict__ b1, const float* __restrict__ W2,
    const float* __restrict__ b2, const float* __restrict__ Wg,
    const float* __restrict__ bg, float* __restrict__ wws,
    float* __restrict__ gws) {
  const int bb = blockIdx.x;
  const int t = threadIdx.x;
  __shared__ float xs[512];
  __shared__ float psum[32][9];   // +1 pad
  __shared__ float hs[32];
  __shared__ float cs[32];
  const float* x = ctx + (bb << 9);
  xs[t] = x[t];
  xs[t + 256] = x[t + 256];
  __syncthreads();
  {
    const int e = t >> 3, part = t & 7;
    const float* wrow = W1 + e * 512 + part * 64;
    const float* xp = xs + part * 64;
    float a = 0.f;
#pragma unroll
    for (int m = 0; m < 64; ++m) a = fmaf(wrow[m], xp[m], a);
    psum[e][part] = a;
  }
  __syncthreads();
  if (t < 32) {
    float a = 0.f;
#pragma unroll
    for (int p = 0; p < 8; ++p) a += psum[t][p];
    hs[t] = fmaxf(a + b1[t], 0.f);
  }
  __syncthreads();
  if (t < 32) {
    const float* wrow = W2 + (t << 5);
    float a = 0.f;
#pragma unroll
    for (int k = 0; k < 32; ++k) a = fmaf(wrow[k], hs[k], a);
    float c = a + b2[t];
    cs[t] = c;
    wws[(bb << 5) + t] = c * c;
  }
  __syncthreads();
  if (t == 0) {
    float a = 0.f;
#pragma unroll
    for (int k = 0; k < 32; ++k) a = fmaf(Wg[k], cs[k], a);
    float g = a + bg[0];
    gws[bb] = 1.f / (1.f + __expf(-g));
  }
}

// med3 sorted-insert of value v into desc list hv[0..9] (values only, exact)
#define MED3_INSERT(hv, v)                                           \
  do {                                                               \
    _Pragma("unroll") for (int k = 9; k >= 1; --k)                   \
        hv[k] = __builtin_amdgcn_fmed3f((v), hv[k - 1], hv[k]);      \
    hv[0] = fmaxf(hv[0], (v));                                       \
  } while (0)

// strict-> shift insert: equal values keep earlier-inserted (lower j) above
#define TOP10_INSERT(av, aj, v, jn)                           \
  do {                                                        \
    _Pragma("unroll") for (int k = 9; k >= 1; --k) {          \
      bool gk = (v) > av[k];                                  \
      bool gk1 = (v) > av[k - 1];                             \
      av[k] = gk ? (gk1 ? av[k - 1] : (v)) : av[k];           \
      aj[k] = gk ? (gk1 ? aj[k - 1] : (jn)) : aj[k];          \
    }                                                         \
    bool g0 = (v) > av[0];                                    \
    av[0] = g0 ? (v) : av[0];                                 \
    aj[0] = g0 ? (jn) : aj[0];                                \
  } while (0)

// shared logit computation for 4 consecutive j (identical expression tree in
// both passes -> bit-identical values; proven by R6 absmax)
__device__ __forceinline__ void compute4(const nf4* __restrict__ eb,
                                         const f2* sv2, int j0, float& a0,
                                         float& a1, float& a2, float& a3) {
  const nf4* p0 = eb + ((j0 + 0) << 3);
  const nf4* p1 = eb + ((j0 + 1) << 3);
  const nf4* p2 = eb + ((j0 + 2) << 3);
  const nf4* p3 = eb + ((j0 + 3) << 3);
  f2 c0 = {0.f, 0.f}, c1 = {0.f, 0.f}, c2 = {0.f, 0.f}, c3 = {0.f, 0.f};
#pragma unroll
  for (int q = 0; q < 8; ++q) {
    nf4 v0 = p0[q], v1 = p1[q], v2 = p2[q], v3 = p3[q];
    c0 += sv2[2 * q] * __builtin_shufflevector(v0, v0, 0, 1);
    c0 += sv2[2 * q + 1] * __builtin_shufflevector(v0, v0, 2, 3);
    c1 += sv2[2 * q] * __builtin_shufflevector(v1, v1, 0, 1);
    c1 += sv2[2 * q + 1] * __builtin_shufflevector(v1, v1, 2, 3);
    c2 += sv2[2 * q] * __builtin_shufflevector(v2, v2, 0, 1);
    c2 += sv2[2 * q + 1] * __builtin_shufflevector(v2, v2, 2, 3);
    c3 += sv2[2 * q] * __builtin_shufflevector(v3, v3, 0, 1);
    c3 += sv2[2 * q + 1] * __builtin_shufflevector(v3, v3, 2, 3);
  }
  a0 = c0.x + c0.y;
  a1 = c1.x + c1.y;
  a2 = c2.x + c2.y;
  a3 = c3.x + c3.y;
}

// ---------------- K2: 4-wave block per 64 rows; two-pass exact top-10 -------
__global__ __launch_bounds__(256, 7) void cdm_k2(
    const float* __restrict__ emb, const float* __restrict__ wws,
    const float* __restrict__ gws, float* __restrict__ out) {
  const int lane = threadIdx.x & 63;
  const int w = threadIdx.x >> 6;    // j-quarter 0..3
  const int G = __builtin_amdgcn_readfirstlane(blockIdx.x);
  const int r0 = G << 6;             // 64 rows per block, same b
  const int b = r0 >> 9;
  const int i = (r0 + lane) & 511;
  const int jbase = __builtin_amdgcn_readfirstlane(w << 7);

  // LDS overlay: mv[4][10][64] f32 (10240 B) aliases the head of
  // bfj[64][4][10] u64 (20480 B); cnt[64][4] u32 behind (1024 B). 21504 B.
  __shared__ __align__(16) unsigned char lds_raw[21504];
  float (*mv)[10][64] = reinterpret_cast<float(*)[10][64]>(lds_raw);
  unsigned long long* bfj = reinterpret_cast<unsigned long long*>(lds_raw);
  unsigned int* cntp = reinterpret_cast<unsigned int*>(lds_raw + 20480);

  // sv2[q] = (c^2)[b] * emb[i] as f2 pairs (per-lane)
  f2 sv2[16];
  {
    const f2* wb = reinterpret_cast<const f2*>(wws + (b << 5));
    const f2* ei = reinterpret_cast<const f2*>(emb + (i << 5));
#pragma unroll
    for (int q = 0; q < 16; ++q) sv2[q] = wb[q] * ei[q];
  }
  const float gateb = gws[b];
  const nf4* eb = reinterpret_cast<const nf4*>(emb);

  // ---- pass 1: branchless top-10 values (med3) over my 128-j quarter ------
  float hv[10];
#pragma unroll
  for (int k = 0; k < 10; ++k) hv[k] = -1e30f;
  for (int t = 0; t < 32; ++t) {
    float a0, a1, a2, a3;
    compute4(eb, sv2, jbase + (t << 2), a0, a1, a2, a3);
    MED3_INSERT(hv, a0);
    MED3_INSERT(hv, a1);
    MED3_INSERT(hv, a2);
    MED3_INSERT(hv, a3);
  }

  // ---- publish; merge to exact global 10th value T ------------------------
#pragma unroll
  for (int k = 0; k < 10; ++k) mv[w][k][lane] = hv[k];
  __syncthreads();  // B1

  float fv[10];
#pragma unroll
  for (int k = 0; k < 10; ++k) fv[k] = -1e30f;
  for (int h = 0; h < 4; ++h) {
#pragma unroll
    for (int k = 0; k < 10; ++k) {
      float v = mv[h][k][lane];
      MED3_INSERT(fv, v);
    }
  }
  const float T = fv[9];
  __syncthreads();  // B2: mv reads done; bfj (aliasing mv) may now be written

  // ---- pass 2: recompute identically, collect a >= T (no atomics) ---------
  {
    unsigned int c = 0;
    unsigned long long* myb = bfj + ((unsigned)((lane << 2) | w)) * 10u;
    for (int t = 0; t < 32; ++t) {
      const int j0 = jbase + (t << 2);
      float a0, a1, a2, a3;
      compute4(eb, sv2, j0, a0, a1, a2, a3);
      if (a0 >= T) {
        if (c < 10)
          myb[c] = ((unsigned long long)(unsigned)(j0) << 32) |
                   (unsigned)__float_as_uint(a0);
        ++c;
      }
      if (a1 >= T) {
        if (c < 10)
          myb[c] = ((unsigned long long)(unsigned)(j0 + 1) << 32) |
                   (unsigned)__float_as_uint(a1);
        ++c;
      }
      if (a2 >= T) {
        if (c < 10)
          myb[c] = ((unsigned long long)(unsigned)(j0 + 2) << 32) |
                   (unsigned)__float_as_uint(a2);
        ++c;
      }
      if (a3 >= T) {
        if (c < 10)
          myb[c] = ((unsigned long long)(unsigned)(j0 + 3) << 32) |
                   (unsigned)__float_as_uint(a3);
        ++c;
      }
    }
    cntp[(lane << 2) | w] = c < 10u ? c : 10u;
  }
  __syncthreads();  // B3

  // ---- assembly (every wave, lane=row): concat quarters 0..3 = ascending j,
  //      exact strict-> insert (branchless; masked lanes insert -1e30 no-op)
  float fvv[10];
  int fjj[10];
#pragma unroll
  for (int k = 0; k < 10; ++k) { fvv[k] = -1e30f; fjj[k] = 0; }
  for (int h = 0; h < 4; ++h) {
    const int n = (int)cntp[(lane << 2) | h];
    const unsigned long long* rb = bfj + ((unsigned)((lane << 2) | h)) * 10u;
    for (int k = 0; k < 10; ++k) {
      if (__all(k >= n)) break;
      unsigned long long pk = rb[k];
      float v = (k < n) ? __uint_as_float((unsigned)pk) : -1e30f;
      int jn = (int)(pk >> 32);
      TOP10_INSERT(fvv, fjj, v, jn);
    }
  }

  // ---- epilogue: wave w fills rows [16w,16w+16), waits, scatters them -----
  float oval[10];
#pragma unroll
  for (int k = 0; k < 10; ++k) oval[k] = gateb / (1.f + __expf(-fvv[k]));

  nf4 z4 = {0.f, 0.f, 0.f, 0.f};
  nf4* zb = reinterpret_cast<nf4*>(out + ((size_t)(r0 + (w << 4)) << 9));
#pragma unroll 8
  for (int k = 0; k < 32; ++k) zb[(k << 6) + lane] = z4;
  asm volatile("s_waitcnt vmcnt(0)" ::: "memory");
  if ((lane >> 4) == w) {
    float* rb = out + ((size_t)(r0 + lane) << 9);
#pragma unroll
    for (int k = 0; k < 10; ++k) rb[fjj[k]] = oval[k];
  }
}

extern "C" void kernel_launch(void* const* d_in, const int* in_sizes, int n_in,
                              void* d_out, int out_size, void* d_ws,
                              size_t ws_size, hipStream_t stream) {
  const float* ctx = (const float*)d_in[0];
  const float* emb = (const float*)d_in[1];
  const float* W1 = (const float*)d_in[2];
  const float* b1 = (const float*)d_in[3];
  const float* W2 = (const float*)d_in[4];
  const float* b2 = (const float*)d_in[5];
  const float* Wg = (const float*)d_in[6];
  const float* bg = (const float*)d_in[7];
  float* out = (float*)d_out;
  float* wws = (float*)d_ws;            // 256*32 floats: c^2
  float* gws = wws + BATCH * EMBED_DIM; // 256 floats: gate

  cdm_k1<<<BATCH, 256, 0, stream>>>(ctx, W1, b1, W2, b2, Wg, bg, wws, gws);
  cdm_k2<<<2048, 256, 0, stream>>>(emb, wws, gws, out);
}

// Round 8
// 392.539 us; speedup vs baseline: 1.0335x; 1.0335x over previous
//
#include <hip/hip_runtime.h>
#include <hip/hip_bf16.h>

// CausalDiscoveryModule: B=256, N=512, E=32, IN=512, K=10
// out[b,i,j] = gate_b * sigmoid(logit) on per-(b,i)-row top-10 of j, else 0
// logit = sum_e (c_b^2 * emb_i)[e] * emb_j[e]
//
// R8 = R5 skeleton (2-way j-split, 2048x128, f2 packed compute — proven
// v_pk_fma codegen and clean 262144KB WRITE epilogue) with the divergent
// while(__any) insert loop replaced by the branchless med3 two-pass:
//   pass1: top-10 VALUES via v_med3_f32 (10 instr/candidate, no divergence)
//   merge: exact global 10th T from the 2 half-lists (LDS, lane-minor)
//   pass2: recompute bit-identically (same inlined helper), collect a>=T into
//          lane-minor LDS buffers (bank=lane&31, 2-way alias = free), no
//          atomics (per-lane private counters).
//   assembly: concat halves (ascending j), exact strict-> insert (~10 items).
//   epilogue: EXACT R5 form — wave w fills rows [32w,32w+32) (64KB), vmcnt(0),
//          scatters those rows immediately (scatters hit L2 => no extra HBM).

#define NUM_VARS 512
#define EMBED_DIM 32
#define IN_DIM 512
#define BATCH 256

typedef float nf4 __attribute__((ext_vector_type(4)));
typedef float f2 __attribute__((ext_vector_type(2)));

// ---------------- K1: context MLP -> w = c^2 [256][32], gate [256] ----------
__global__ __launch_bounds__(256) void cdm_k1(
    const float* __restrict__ ctx, const float* __restrict__ W1,
    const float* __restrict__ b1, const float* __restrict__ W2,
    const float* __restrict__ b2, const float* __restrict__ Wg,
    const float* __restrict__ bg, float* __restrict__ wws,
    float* __restrict__ gws) {
  const int bb = blockIdx.x;
  const int t = threadIdx.x;
  __shared__ float xs[512];
  __shared__ float psum[32][9];   // +1 pad
  __shared__ float hs[32];
  __shared__ float cs[32];
  const float* x = ctx + (bb << 9);
  xs[t] = x[t];
  xs[t + 256] = x[t + 256];
  __syncthreads();
  {
    const int e = t >> 3, part = t & 7;
    const float* wrow = W1 + e * 512 + part * 64;
    const float* xp = xs + part * 64;
    float a = 0.f;
#pragma unroll
    for (int m = 0; m < 64; ++m) a = fmaf(wrow[m], xp[m], a);
    psum[e][part] = a;
  }
  __syncthreads();
  if (t < 32) {
    float a = 0.f;
#pragma unroll
    for (int p = 0; p < 8; ++p) a += psum[t][p];
    hs[t] = fmaxf(a + b1[t], 0.f);
  }
  __syncthreads();
  if (t < 32) {
    const float* wrow = W2 + (t << 5);
    float a = 0.f;
#pragma unroll
    for (int k = 0; k < 32; ++k) a = fmaf(wrow[k], hs[k], a);
    float c = a + b2[t];
    cs[t] = c;
    wws[(bb << 5) + t] = c * c;
  }
  __syncthreads();
  if (t == 0) {
    float a = 0.f;
#pragma unroll
    for (int k = 0; k < 32; ++k) a = fmaf(Wg[k], cs[k], a);
    float g = a + bg[0];
    gws[bb] = 1.f / (1.f + __expf(-g));
  }
}

// med3 sorted-insert of value v into desc list hv[0..9] (values only, exact)
#define MED3_INSERT(hv, v)                                           \
  do {                                                               \
    _Pragma("unroll") for (int k = 9; k >= 1; --k)                   \
        hv[k] = __builtin_amdgcn_fmed3f((v), hv[k - 1], hv[k]);      \
    hv[0] = fmaxf(hv[0], (v));                                       \
  } while (0)

// strict-> shift insert: equal values keep earlier-inserted (lower j) above
#define TOP10_INSERT(av, aj, v, jn)                           \
  do {                                                        \
    _Pragma("unroll") for (int k = 9; k >= 1; --k) {          \
      bool gk = (v) > av[k];                                  \
      bool gk1 = (v) > av[k - 1];                             \
      av[k] = gk ? (gk1 ? av[k - 1] : (v)) : av[k];           \
      aj[k] = gk ? (gk1 ? aj[k - 1] : (jn)) : aj[k];          \
    }                                                         \
    bool g0 = (v) > av[0];                                    \
    av[0] = g0 ? (v) : av[0];                                 \
    aj[0] = g0 ? (jn) : aj[0];                                \
  } while (0)

// R5's exact packed-f2 logit computation for 4 consecutive j. Used in BOTH
// passes (inlined identically) -> bit-identical values.
__device__ __forceinline__ void compute4(const f2* __restrict__ eb,
                                         const f2* sv2, int j0, float& a0,
                                         float& a1, float& a2, float& a3) {
  const f2* e0 = eb + ((j0 + 0) << 4);
  const f2* e1 = eb + ((j0 + 1) << 4);
  const f2* e2 = eb + ((j0 + 2) << 4);
  const f2* e3 = eb + ((j0 + 3) << 4);
  f2 c0 = {0.f, 0.f}, c1 = {0.f, 0.f}, c2 = {0.f, 0.f}, c3 = {0.f, 0.f};
#pragma unroll
  for (int q = 0; q < 16; ++q) {
    c0 += sv2[q] * e0[q];   // v_pk_fma_f32
    c1 += sv2[q] * e1[q];
    c2 += sv2[q] * e2[q];
    c3 += sv2[q] * e3[q];
  }
  a0 = c0.x + c0.y;
  a1 = c1.x + c1.y;
  a2 = c2.x + c2.y;
  a3 = c3.x + c3.y;
}

// ---------------- K2: 2-wave block per 64 rows; two-pass exact top-10 -------
__global__ __launch_bounds__(128, 4) void cdm_k2(
    const float* __restrict__ emb, const float* __restrict__ wws,
    const float* __restrict__ gws, float* __restrict__ out) {
  const int lane = threadIdx.x & 63;
  const int w = threadIdx.x >> 6;    // half 0: j in [0,256), 1: [256,512)
  const int G = __builtin_amdgcn_readfirstlane(blockIdx.x);
  const int r0 = G << 6;             // 64 rows per block, same b
  const int b = r0 >> 9;
  const int i = (r0 + lane) & 511;
  const int jbase = __builtin_amdgcn_readfirstlane(w << 8);

  __shared__ float mv[2][10][64];    // pass-1 value lists (lane-minor)
  __shared__ float bval[2][10][64];  // candidate values (lane-minor)
  __shared__ int bidx[2][10][64];    // candidate j (lane-minor)
  __shared__ int cnt[2][64];

  // sv2[q] = (c^2)[b] * emb[i] as f2 pairs (per-lane)
  f2 sv2[16];
  {
    const f2* wb = reinterpret_cast<const f2*>(wws + (b << 5));
    const f2* ei = reinterpret_cast<const f2*>(emb + (i << 5));
#pragma unroll
    for (int q = 0; q < 16; ++q) sv2[q] = wb[q] * ei[q];
  }
  const float gateb = gws[b];
  const f2* eb = reinterpret_cast<const f2*>(emb);

  // ---- pass 1: branchless top-10 values (med3) over my 256-j half ---------
  float hv[10];
#pragma unroll
  for (int k = 0; k < 10; ++k) hv[k] = -1e30f;
  for (int t = 0; t < 64; ++t) {
    float a0, a1, a2, a3;
    compute4(eb, sv2, jbase + (t << 2), a0, a1, a2, a3);
    MED3_INSERT(hv, a0);
    MED3_INSERT(hv, a1);
    MED3_INSERT(hv, a2);
    MED3_INSERT(hv, a3);
  }

  // ---- publish; merge to exact global 10th value T ------------------------
#pragma unroll
  for (int k = 0; k < 10; ++k) mv[w][k][lane] = hv[k];
  __syncthreads();  // B1

  float fv[10];
#pragma unroll
  for (int k = 0; k < 10; ++k) fv[k] = -1e30f;
#pragma unroll
  for (int h = 0; h < 2; ++h) {
#pragma unroll
    for (int k = 0; k < 10; ++k) {
      float v = mv[h][k][lane];
      MED3_INSERT(fv, v);
    }
  }
  const float T = fv[9];

  // ---- pass 2: recompute identically, collect a >= T (no atomics) ---------
  {
    int c = 0;
    for (int t = 0; t < 64; ++t) {
      const int j0 = jbase + (t << 2);
      float a0, a1, a2, a3;
      compute4(eb, sv2, j0, a0, a1, a2, a3);
      if (a0 >= T) {
        if (c < 10) { bval[w][c][lane] = a0; bidx[w][c][lane] = j0; }
        ++c;
      }
      if (a1 >= T) {
        if (c < 10) { bval[w][c][lane] = a1; bidx[w][c][lane] = j0 + 1; }
        ++c;
      }
      if (a2 >= T) {
        if (c < 10) { bval[w][c][lane] = a2; bidx[w][c][lane] = j0 + 2; }
        ++c;
      }
      if (a3 >= T) {
        if (c < 10) { bval[w][c][lane] = a3; bidx[w][c][lane] = j0 + 3; }
        ++c;
      }
    }
    cnt[w][lane] = c < 10 ? c : 10;
  }
  __syncthreads();  // B2

  // ---- assembly (lane=row): concat halves 0,1 = ascending j, exact insert -
  float fvv[10];
  int fjj[10];
#pragma unroll
  for (int k = 0; k < 10; ++k) { fvv[k] = -1e30f; fjj[k] = 0; }
#pragma unroll
  for (int h = 0; h < 2; ++h) {
    const int n = cnt[h][lane];
    for (int k = 0; k < 10; ++k) {
      if (__all(k >= n)) break;
      float v = (k < n) ? bval[h][k][lane] : -1e30f;
      int jn = bidx[h][k][lane];
      TOP10_INSERT(fvv, fjj, v, jn);
    }
  }

  // ---- epilogue (EXACT R5): wave w fills rows [32w,32w+32), scatters them -
  float oval[10];
#pragma unroll
  for (int k = 0; k < 10; ++k) oval[k] = gateb / (1.f + __expf(-fvv[k]));

  nf4 z4 = {0.f, 0.f, 0.f, 0.f};
  nf4* zb4 = reinterpret_cast<nf4*>(out + ((size_t)(r0 + (w << 5)) << 9));
#pragma unroll 8
  for (int k = 0; k < 64; ++k) zb4[(k << 6) + lane] = z4;
  asm volatile("s_waitcnt vmcnt(0)" ::: "memory");
  if ((lane >> 5) == w) {
    float* rbase = out + ((size_t)(r0 + lane) << 9);
#pragma unroll
    for (int k = 0; k < 10; ++k) rbase[fjj[k]] = oval[k];
  }
}

extern "C" void kernel_launch(void* const* d_in, const int* in_sizes, int n_in,
                              void* d_out, int out_size, void* d_ws,
                              size_t ws_size, hipStream_t stream) {
  const float* ctx = (const float*)d_in[0];
  const float* emb = (const float*)d_in[1];
  const float* W1 = (const float*)d_in[2];
  const float* b1 = (const float*)d_in[3];
  const float* W2 = (const float*)d_in[4];
  const float* b2 = (const float*)d_in[5];
  const float* Wg = (const float*)d_in[6];
  const float* bg = (const float*)d_in[7];
  float* out = (float*)d_out;
  float* wws = (float*)d_ws;            // 256*32 floats: c^2
  float* gws = wws + BATCH * EMBED_DIM; // 256 floats: gate

  cdm_k1<<<BATCH, 256, 0, stream>>>(ctx, W1, b1, W2, b2, Wg, bg, wws, gws);
  cdm_k2<<<2048, 128, 0, stream>>>(emb, wws, gws, out);
}

// Round 9
// 385.649 us; speedup vs baseline: 1.0520x; 1.0179x over previous
//
#include <hip/hip_runtime.h>
#include <hip/hip_bf16.h>

// CausalDiscoveryModule: B=256, N=512, E=32, IN=512, K=10
// out[b,i,j] = gate_b * sigmoid(logit) on per-(b,i)-row top-10 of j, else 0
// logit = sum_e (c_b^2 * emb_i)[e] * emb_j[e]
//
// R9 = R8's branchless med3 two-pass (exact), with two measured fixes:
//  - compute4: 4 contiguous j-rows from ONE base pointer -> 32 dwordx4 loads
//    with immediate offsets (1 addr calc per group, was ~128 addr VALU ops).
//    Numerics = R6/R7 form (pairwise f2 via shufflevector) — proven absmax.
//  - epilogue: R3's LDS-tile assembly (the only form that measured WRITE_SIZE
//    == 262 MB exactly). 4-row tiles, per-wave-private slices, NT stores.
//  - LDS overlay: lists (15.9 KB) aliased by tiles (16.4 KB) -> 8 blocks/CU.

#define NUM_VARS 512
#define EMBED_DIM 32
#define IN_DIM 512
#define BATCH 256

typedef float nf4 __attribute__((ext_vector_type(4)));
typedef float f2 __attribute__((ext_vector_type(2)));

// ---------------- K1: context MLP -> w = c^2 [256][32], gate [256] ----------
__global__ __launch_bounds__(256) void cdm_k1(
    const float* __restrict__ ctx, const float* __restrict__ W1,
    const float* __restrict__ b1, const float* __restrict__ W2,
    const float* __restrict__ b2, const float* __restrict__ Wg,
    const float* __restrict__ bg, float* __restrict__ wws,
    float* __restrict__ gws) {
  const int bb = blockIdx.x;
  const int t = threadIdx.x;
  __shared__ float xs[512];
  __shared__ float psum[32][9];   // +1 pad
  __shared__ float hs[32];
  __shared__ float cs[32];
  const float* x = ctx + (bb << 9);
  xs[t] = x[t];
  xs[t + 256] = x[t + 256];
  __syncthreads();
  {
    const int e = t >> 3, part = t & 7;
    const float* wrow = W1 + e * 512 + part * 64;
    const float* xp = xs + part * 64;
    float a = 0.f;
#pragma unroll
    for (int m = 0; m < 64; ++m) a = fmaf(wrow[m], xp[m], a);
    psum[e][part] = a;
  }
  __syncthreads();
  if (t < 32) {
    float a = 0.f;
#pragma unroll
    for (int p = 0; p < 8; ++p) a += psum[t][p];
    hs[t] = fmaxf(a + b1[t], 0.f);
  }
  __syncthreads();
  if (t < 32) {
    const float* wrow = W2 + (t << 5);
    float a = 0.f;
#pragma unroll
    for (int k = 0; k < 32; ++k) a = fmaf(wrow[k], hs[k], a);
    float c = a + b2[t];
    cs[t] = c;
    wws[(bb << 5) + t] = c * c;
  }
  __syncthreads();
  if (t == 0) {
    float a = 0.f;
#pragma unroll
    for (int k = 0; k < 32; ++k) a = fmaf(Wg[k], cs[k], a);
    float g = a + bg[0];
    gws[bb] = 1.f / (1.f + __expf(-g));
  }
}

// med3 sorted-insert of value v into desc list hv[0..9] (values only, exact)
#define MED3_INSERT(hv, v)                                           \
  do {                                                               \
    _Pragma("unroll") for (int k = 9; k >= 1; --k)                   \
        hv[k] = __builtin_amdgcn_fmed3f((v), hv[k - 1], hv[k]);      \
    hv[0] = fmaxf(hv[0], (v));                                       \
  } while (0)

// strict-> shift insert: equal values keep earlier-inserted (lower j) above
#define TOP10_INSERT(av, aj, v, jn)                           \
  do {                                                        \
    _Pragma("unroll") for (int k = 9; k >= 1; --k) {          \
      bool gk = (v) > av[k];                                  \
      bool gk1 = (v) > av[k - 1];                             \
      av[k] = gk ? (gk1 ? av[k - 1] : (v)) : av[k];           \
      aj[k] = gk ? (gk1 ? aj[k - 1] : (jn)) : aj[k];          \
    }                                                         \
    bool g0 = (v) > av[0];                                    \
    av[0] = g0 ? (v) : av[0];                                 \
    aj[0] = g0 ? (jn) : aj[0];                                \
  } while (0)

// 4 contiguous j-rows, one base pointer, imm-offset dwordx4 loads. Pairwise
// f2 accumulation (shufflevector split) — bit-identical across both passes
// and to R6/R7 (absmax-proven).
__device__ __forceinline__ void compute4(const float* __restrict__ embf,
                                         const f2* sv2, int j0, float& a0,
                                         float& a1, float& a2, float& a3) {
  const nf4* p = reinterpret_cast<const nf4*>(embf + (j0 << 5));
  f2 c0 = {0.f, 0.f}, c1 = {0.f, 0.f}, c2 = {0.f, 0.f}, c3 = {0.f, 0.f};
#pragma unroll
  for (int q = 0; q < 8; ++q) {
    nf4 v0 = p[q], v1 = p[8 + q], v2 = p[16 + q], v3 = p[24 + q];
    c0 += sv2[2 * q] * __builtin_shufflevector(v0, v0, 0, 1);
    c0 += sv2[2 * q + 1] * __builtin_shufflevector(v0, v0, 2, 3);
    c1 += sv2[2 * q] * __builtin_shufflevector(v1, v1, 0, 1);
    c1 += sv2[2 * q + 1] * __builtin_shufflevector(v1, v1, 2, 3);
    c2 += sv2[2 * q] * __builtin_shufflevector(v2, v2, 0, 1);
    c2 += sv2[2 * q + 1] * __builtin_shufflevector(v2, v2, 2, 3);
    c3 += sv2[2 * q] * __builtin_shufflevector(v3, v3, 0, 1);
    c3 += sv2[2 * q + 1] * __builtin_shufflevector(v3, v3, 2, 3);
  }
  a0 = c0.x + c0.y;
  a1 = c1.x + c1.y;
  a2 = c2.x + c2.y;
  a3 = c3.x + c3.y;
}

// ---------------- K2: 2-wave block per 64 rows; two-pass exact top-10 -------
__global__ __launch_bounds__(128, 4) void cdm_k2(
    const float* __restrict__ emb, const float* __restrict__ wws,
    const float* __restrict__ gws, float* __restrict__ out) {
  const int lane = threadIdx.x & 63;
  const int w = threadIdx.x >> 6;    // half 0: j in [0,256), 1: [256,512)
  const int G = __builtin_amdgcn_readfirstlane(blockIdx.x);
  const int r0 = G << 6;             // 64 rows per block, same b
  const int b = r0 >> 9;
  const int i = (r0 + lane) & 511;
  const int jbase = __builtin_amdgcn_readfirstlane(w << 8);

  // LDS overlay, 16384 B:
  //   lists: mv[2][10][64] f32 @0 (5120) | bval[2][10][64] @5120 (5120)
  //          bidx[2][10][64] @10240 (5120) | cnt[2][64] @15360 (512)
  //   tiles (after B3, alias everything): wave w -> floats @ w*8192 B (2048 f)
  __shared__ __align__(16) unsigned char lraw[16384];
  float (*mv)[10][64] = reinterpret_cast<float(*)[10][64]>(lraw);
  float (*bval)[10][64] = reinterpret_cast<float(*)[10][64]>(lraw + 5120);
  int (*bidx)[10][64] = reinterpret_cast<int(*)[10][64]>(lraw + 10240);
  int (*cnt)[64] = reinterpret_cast<int(*)[64]>(lraw + 15360);

  // sv2[q] = (c^2)[b] * emb[i] as f2 pairs (per-lane)
  f2 sv2[16];
  {
    const f2* wb = reinterpret_cast<const f2*>(wws + (b << 5));
    const f2* ei = reinterpret_cast<const f2*>(emb + (i << 5));
#pragma unroll
    for (int q = 0; q < 16; ++q) sv2[q] = wb[q] * ei[q];
  }
  const float gateb = gws[b];

  // ---- pass 1: branchless top-10 values (med3) over my 256-j half ---------
  float hv[10];
#pragma unroll
  for (int k = 0; k < 10; ++k) hv[k] = -1e30f;
  for (int t = 0; t < 64; ++t) {
    float a0, a1, a2, a3;
    compute4(emb, sv2, jbase + (t << 2), a0, a1, a2, a3);
    MED3_INSERT(hv, a0);
    MED3_INSERT(hv, a1);
    MED3_INSERT(hv, a2);
    MED3_INSERT(hv, a3);
  }

  // ---- publish; merge to exact global 10th value T ------------------------
#pragma unroll
  for (int k = 0; k < 10; ++k) mv[w][k][lane] = hv[k];
  __syncthreads();  // B1

  float fv[10];
#pragma unroll
  for (int k = 0; k < 10; ++k) fv[k] = -1e30f;
#pragma unroll
  for (int h = 0; h < 2; ++h) {
#pragma unroll
    for (int k = 0; k < 10; ++k) {
      float v = mv[h][k][lane];
      MED3_INSERT(fv, v);
    }
  }
  const float T = fv[9];

  // ---- pass 2: recompute identically, collect a >= T (no atomics) ---------
  {
    int c = 0;
    for (int t = 0; t < 64; ++t) {
      const int j0 = jbase + (t << 2);
      float a0, a1, a2, a3;
      compute4(emb, sv2, j0, a0, a1, a2, a3);
      if (a0 >= T) {
        if (c < 10) { bval[w][c][lane] = a0; bidx[w][c][lane] = j0; }
        ++c;
      }
      if (a1 >= T) {
        if (c < 10) { bval[w][c][lane] = a1; bidx[w][c][lane] = j0 + 1; }
        ++c;
      }
      if (a2 >= T) {
        if (c < 10) { bval[w][c][lane] = a2; bidx[w][c][lane] = j0 + 2; }
        ++c;
      }
      if (a3 >= T) {
        if (c < 10) { bval[w][c][lane] = a3; bidx[w][c][lane] = j0 + 3; }
        ++c;
      }
    }
    cnt[w][lane] = c < 10 ? c : 10;
  }
  __syncthreads();  // B2

  // ---- assembly (lane=row): concat halves 0,1 = ascending j, exact insert -
  float fvv[10];
  int fjj[10];
#pragma unroll
  for (int k = 0; k < 10; ++k) { fvv[k] = -1e30f; fjj[k] = 0; }
#pragma unroll
  for (int h = 0; h < 2; ++h) {
    const int n = cnt[h][lane];
    for (int k = 0; k < 10; ++k) {
      if (__all(k >= n)) break;
      float v = (k < n) ? bval[h][k][lane] : -1e30f;
      int jn = bidx[h][k][lane];
      TOP10_INSERT(fvv, fjj, v, jn);
    }
  }
  __syncthreads();  // B3: lists dead; tile region (aliasing them) may be used

  // ---- epilogue: R3-style LDS tiles. Wave w writes rows [32w,32w+32) in
  //      8 tiles of 4 rows; per-wave-private slice, no cross-wave sync. -----
  float oval[10];
#pragma unroll
  for (int k = 0; k < 10; ++k) oval[k] = gateb / (1.f + __expf(-fvv[k]));

  float* tb = reinterpret_cast<float*>(lraw) + (w << 11);  // 2048 floats
  nf4* tb4 = reinterpret_cast<nf4*>(tb);
  nf4 z4 = {0.f, 0.f, 0.f, 0.f};
  for (int t = 0; t < 8; ++t) {
    asm volatile("s_waitcnt lgkmcnt(0)" ::: "memory");
#pragma unroll
    for (int k = 0; k < 8; ++k) tb4[(k << 6) + lane] = z4;
    asm volatile("s_waitcnt lgkmcnt(0)" ::: "memory");
    if ((lane >> 2) == ((w << 3) | t)) {
      const int lrow = lane & 3;
#pragma unroll
      for (int k = 0; k < 10; ++k) tb[(lrow << 9) + fjj[k]] = oval[k];
    }
    asm volatile("s_waitcnt lgkmcnt(0)" ::: "memory");
    nf4* og = reinterpret_cast<nf4*>(out +
        ((size_t)(r0 + (w << 5) + (t << 2)) << 9));
#pragma unroll
    for (int k = 0; k < 8; ++k)
      __builtin_nontemporal_store(tb4[(k << 6) + lane], &og[(k << 6) + lane]);
  }
}

extern "C" void kernel_launch(void* const* d_in, const int* in_sizes, int n_in,
                              void* d_out, int out_size, void* d_ws,
                              size_t ws_size, hipStream_t stream) {
  const float* ctx = (const float*)d_in[0];
  const float* emb = (const float*)d_in[1];
  const float* W1 = (const float*)d_in[2];
  const float* b1 = (const float*)d_in[3];
  const float* W2 = (const float*)d_in[4];
  const float* b2 = (const float*)d_in[5];
  const float* Wg = (const float*)d_in[6];
  const float* bg = (const float*)d_in[7];
  float* out = (float*)d_out;
  float* wws = (float*)d_ws;            // 256*32 floats: c^2
  float* gws = wws + BATCH * EMBED_DIM; // 256 floats: gate

  cdm_k1<<<BATCH, 256, 0, stream>>>(ctx, W1, b1, W2, b2, Wg, bg, wws, gws);
  cdm_k2<<<2048, 128, 0, stream>>>(emb, wws, gws, out);
}